// Round 4
// baseline (16.141 us; speedup 1.0000x reference)
//
#include <hip/hip_runtime.h>

#define HEADN   2000
#define NF4     500      // float4 per row head
#define HALF4   250      // float4 per half-row
#define NSAMP   100
#define KC      10
#define CLIPV   20.0f
#define BATCH   2048
#define NCLASS  50000
#define TAILSCL 480.0f   // (50000-2000)/100

__device__ __forceinline__ float clipf(float x) {
    return fminf(fmaxf(x, -CLIPV), CLIPV);
}

// fast softplus via hardware v_exp_f32/v_log_f32; x pre-clipped to [-20,20]
__device__ __forceinline__ float sp(float x) {
    return __logf(1.0f + __expf(x));
}

__device__ __forceinline__ float sp4(float4 v) {
    return (sp(clipf(v.x)) + sp(clipf(v.y))) + (sp(clipf(v.z)) + sp(clipf(v.w)));
}

// 2 waves per row: 1024 blocks x 256 threads; waves {0,1}->row0, {2,3}->row1.
__global__ __launch_bounds__(256) void row_loss_wave2(
        const float* __restrict__ logits,
        const int*   __restrict__ cand,
        const int*   __restrict__ samp,
        float*       __restrict__ row_out)
{
    const int tid  = threadIdx.x;
    const int lane = tid & 63;
    const int w    = tid >> 6;          // wave 0..3
    const int half = w & 1;             // which half of the row
    const int row  = blockIdx.x * 2 + (w >> 1);
    const float* lg = logits + (size_t)row * NCLASS;

    // ---- issue ALL gathers early so latency hides under head compute ----
    // samples: this wave covers half*50 + (0..49)
    const bool sAct = lane < 50;
    const int  scol = HEADN + (sAct ? samp[half * 50 + lane] : 0);
    const float sval = lg[scol];

    // candidates: both waves load the list (needed for sample masking);
    // only the even wave gathers the logit values / contributes term1.
    const int clm = (lane < KC) ? cand[row * KC + lane] : -1;
    float cval = 0.f;
    if (half == 0 && clm >= 0) cval = lg[clm];

    const int c0 = __shfl(clm, 0), c1 = __shfl(clm, 1), c2 = __shfl(clm, 2),
              c3 = __shfl(clm, 3), c4 = __shfl(clm, 4), c5 = __shfl(clm, 5),
              c6 = __shfl(clm, 6), c7 = __shfl(clm, 7), c8 = __shfl(clm, 8),
              c9 = __shfl(clm, 9);

    // head loads: 4 rounds per wave (3 full + 1 partial), issued together
    const float4* lg4 = (const float4*)lg;
    const int base = half * HALF4;
    const bool t3 = lane < HALF4 - 192;            // lanes 0..57
    float4 v0 = lg4[base + lane];
    float4 v1 = lg4[base + lane + 64];
    float4 v2 = lg4[base + lane + 128];
    float4 v3 = lg4[t3 ? (base + lane + 192) : base];

    // ---- compute ----
    float candSum = 0.f, candCnt = 0.f;
    float acc0 = 0.f, acc1 = 0.f;

    acc0 += sp4(v0);
    acc1 += sp4(v1);
    acc0 += sp4(v2);
    if (t3) acc1 += sp4(v3);

    // sampled tail: skip columns equal to any valid candidate
    if (sAct) {
        bool isc = (scol == c0) | (scol == c1) | (scol == c2) | (scol == c3) |
                   (scol == c4) | (scol == c5) | (scol == c6) | (scol == c7) |
                   (scol == c8) | (scol == c9);
        if (!isc) acc0 += TAILSCL * sp(clipf(sval));
    }

    // candidates (even wave): dedupe (dups collapse under .max in the ref)
    if (half == 0 && clm >= 0 && lane < KC) {
        bool distinct = true;
        if (lane > 0 && c0 == clm) distinct = false;
        if (lane > 1 && c1 == clm) distinct = false;
        if (lane > 2 && c2 == clm) distinct = false;
        if (lane > 3 && c3 == clm) distinct = false;
        if (lane > 4 && c4 == clm) distinct = false;
        if (lane > 5 && c5 == clm) distinct = false;
        if (lane > 6 && c6 == clm) distinct = false;
        if (lane > 7 && c7 == clm) distinct = false;
        if (lane > 8 && c8 == clm) distinct = false;
        if (distinct) {
            float x = clipf(cval);
            candSum = x;
            candCnt = 1.f;
            if (clm < HEADN) acc1 -= sp(x);   // masked out of term2
        }
    }

    // ---- per-wave butterfly reduce (3 values) ----
    float acc = acc0 + acc1;
    #pragma unroll
    for (int off = 32; off > 0; off >>= 1) {
        candSum += __shfl_xor(candSum, off);
        candCnt += __shfl_xor(candCnt, off);
        acc     += __shfl_xor(acc, off);
    }

    // ---- cross-wave combine: 2 waves per row ----
    __shared__ float sS[4], sC[4], sA[4];
    if (lane == 0) { sS[w] = candSum; sC[w] = candCnt; sA[w] = acc; }
    __syncthreads();
    if (tid == 0) {            // row 0 of this block (waves 0,1)
        float cs = sS[0] + sS[1], cc = sC[0] + sC[1], a = sA[0] + sA[1];
        float avg = cs / fmaxf(cc, 1.f);
        row_out[row] = sp(-avg) + a;
    }
    if (tid == 128) {          // row 1 of this block (waves 2,3)
        float cs = sS[2] + sS[3], cc = sC[2] + sC[3], a = sA[2] + sA[3];
        float avg = cs / fmaxf(cc, 1.f);
        row_out[row] = sp(-avg) + a;
    }
}

__global__ __launch_bounds__(64) void mean_kernel(
        const float* __restrict__ row, float* __restrict__ out)
{
    const int lane = threadIdx.x;
    const float4* r4 = (const float4*)row;
    float s = 0.f;
    #pragma unroll
    for (int k = 0; k < BATCH / 4 / 64; ++k) {   // 8 float4 per lane
        float4 v = r4[lane + 64 * k];
        s += (v.x + v.y) + (v.z + v.w);
    }
    #pragma unroll
    for (int off = 32; off > 0; off >>= 1) s += __shfl_xor(s, off);
    if (lane == 0) out[0] = s / (float)BATCH;
}

extern "C" void kernel_launch(void* const* d_in, const int* in_sizes, int n_in,
                              void* d_out, int out_size, void* d_ws, size_t ws_size,
                              hipStream_t stream) {
    const float* logits = (const float*)d_in[0];
    const int*   cand   = (const int*)d_in[1];
    const int*   samp   = (const int*)d_in[2];
    float* row_out = (float*)d_ws;          // BATCH floats of scratch
    float* out     = (float*)d_out;

    row_loss_wave2<<<BATCH / 2, 256, 0, stream>>>(logits, cand, samp, row_out);
    mean_kernel<<<1, 64, 0, stream>>>(row_out, out);
}

// Round 5
// 16.020 us; speedup vs baseline: 1.0076x; 1.0076x over previous
//
#include <hip/hip_runtime.h>

#define HEADN   2000
#define NF4     500      // float4 per row head
#define QF4     125      // float4 per quarter-row
#define NSAMP   100
#define KC      10
#define CLIPV   20.0f
#define BATCH   2048
#define NCLASS  50000
#define TAILSCL 480.0f   // (50000-2000)/100

__device__ __forceinline__ float clipf(float x) {
    return fminf(fmaxf(x, -CLIPV), CLIPV);
}

// fast softplus via hardware v_exp_f32/v_log_f32; x pre-clipped to [-20,20]
__device__ __forceinline__ float sp(float x) {
    return __logf(1.0f + __expf(x));
}

__device__ __forceinline__ float sp4(float4 v) {
    return (sp(clipf(v.x)) + sp(clipf(v.y))) + (sp(clipf(v.z)) + sp(clipf(v.w)));
}

// One block per row; 4 independent waves each own a quarter of the head and
// 25 of the 100 sampled-tail columns. Wave 0 additionally owns candidates
// (term1 + head-mask correction). No __syncthreads, no LDS: each wave writes
// its own partial; the mean kernel sums all 8192 partials.
__global__ __launch_bounds__(256) void row_loss_q(
        const float* __restrict__ logits,
        const int*   __restrict__ cand,
        const int*   __restrict__ samp,
        float*       __restrict__ partial)
{
    const int tid  = threadIdx.x;
    const int lane = tid & 63;
    const int w    = tid >> 6;          // quarter index 0..3
    const int row  = blockIdx.x;
    const float* lg = logits + (size_t)row * NCLASS;

    // ---- issue all memory up front: gathers first (longest latency) ----
    const bool  sAct = lane < (NSAMP / 4);                  // 25 per wave
    const int   scol = HEADN + (sAct ? samp[w * (NSAMP / 4) + lane] : 0);
    const float sval = lg[scol];

    const int clm = (lane < KC) ? cand[row * KC + lane] : -1;
    float cval = 0.f;
    if (w == 0 && clm >= 0) cval = lg[clm];                 // wave 0 gathers

    const int c0 = __shfl(clm, 0), c1 = __shfl(clm, 1), c2 = __shfl(clm, 2),
              c3 = __shfl(clm, 3), c4 = __shfl(clm, 4), c5 = __shfl(clm, 5),
              c6 = __shfl(clm, 6), c7 = __shfl(clm, 7), c8 = __shfl(clm, 8),
              c9 = __shfl(clm, 9);

    const float4* lg4 = (const float4*)lg;
    const int  base = w * QF4;
    const bool t1   = lane < QF4 - 64;                      // lanes 0..60
    const float4 v0 = lg4[base + lane];
    const float4 v1 = lg4[t1 ? (base + 64 + lane) : base];

    // ---- compute ----
    float acc0 = sp4(v0);
    float acc1 = t1 ? sp4(v1) : 0.f;

    if (sAct) {
        bool isc = (scol == c0) | (scol == c1) | (scol == c2) | (scol == c3) |
                   (scol == c4) | (scol == c5) | (scol == c6) | (scol == c7) |
                   (scol == c8) | (scol == c9);
        if (!isc) acc0 += TAILSCL * sp(clipf(sval));
    }

    float candSum = 0.f, candCnt = 0.f;
    if (w == 0 && clm >= 0 && lane < KC) {
        // distinct = no earlier equal candidate (dups collapse under .max)
        bool distinct = true;
        if (lane > 0 && c0 == clm) distinct = false;
        if (lane > 1 && c1 == clm) distinct = false;
        if (lane > 2 && c2 == clm) distinct = false;
        if (lane > 3 && c3 == clm) distinct = false;
        if (lane > 4 && c4 == clm) distinct = false;
        if (lane > 5 && c5 == clm) distinct = false;
        if (lane > 6 && c6 == clm) distinct = false;
        if (lane > 7 && c7 == clm) distinct = false;
        if (lane > 8 && c8 == clm) distinct = false;
        if (distinct) {
            float x = clipf(cval);
            candSum = x;
            candCnt = 1.f;
            if (clm < HEADN) acc1 -= sp(x);   // masked out of term2
        }
    }

    // ---- per-wave butterfly reduce ----
    float acc = acc0 + acc1;
    #pragma unroll
    for (int off = 32; off > 0; off >>= 1) {
        acc     += __shfl_xor(acc, off);
        candSum += __shfl_xor(candSum, off);
        candCnt += __shfl_xor(candCnt, off);
    }

    if (lane == 0) {
        if (w == 0) {
            float avg = candSum / fmaxf(candCnt, 1.f);
            acc += sp(-avg);                  // term1 lives in wave 0's partial
        }
        partial[row * 4 + w] = acc;
    }
}

__global__ __launch_bounds__(256) void mean_kernel(
        const float* __restrict__ part, float* __restrict__ out)
{
    const int tid = threadIdx.x;
    const float4* p4 = (const float4*)part;
    float s = 0.f;
    #pragma unroll
    for (int k = 0; k < (BATCH * 4) / 4 / 256; ++k) {   // 8 float4 per thread
        float4 v = p4[tid + 256 * k];
        s += (v.x + v.y) + (v.z + v.w);
    }
    #pragma unroll
    for (int off = 32; off > 0; off >>= 1) s += __shfl_xor(s, off);
    __shared__ float sw[4];
    if ((tid & 63) == 0) sw[tid >> 6] = s;
    __syncthreads();
    if (tid == 0) out[0] = (sw[0] + sw[1] + sw[2] + sw[3]) / (float)BATCH;
}

extern "C" void kernel_launch(void* const* d_in, const int* in_sizes, int n_in,
                              void* d_out, int out_size, void* d_ws, size_t ws_size,
                              hipStream_t stream) {
    const float* logits = (const float*)d_in[0];
    const int*   cand   = (const int*)d_in[1];
    const int*   samp   = (const int*)d_in[2];
    float* partial = (float*)d_ws;          // BATCH*4 floats of scratch
    float* out     = (float*)d_out;

    row_loss_q<<<BATCH, 256, 0, stream>>>(logits, cand, samp, partial);
    mean_kernel<<<1, 256, 0, stream>>>(partial, out);
}